// Round 7
// baseline (826.697 us; speedup 1.0000x reference)
//
#include <hip/hip_runtime.h>

typedef unsigned short u16;
typedef __attribute__((ext_vector_type(8))) short short8;
typedef __attribute__((ext_vector_type(4))) float f32x4;

#define MFMA(a, b, c) __builtin_amdgcn_mfma_f32_16x16x32_bf16((a), (b), (c), 0, 0, 0)

__device__ inline float bf2f(u16 u) {
  union { unsigned int i; float f; } w; w.i = ((unsigned int)u) << 16; return w.f;
}
__device__ inline u16 f2bf(float x) {
  union { float f; unsigned int i; } u; u.f = x;
  unsigned int r = u.i + 0x7fffu + ((u.i >> 16) & 1u);  // RNE
  return (u16)(r >> 16);
}
__device__ inline unsigned int pk2(float a, float b) {
  return (unsigned int)f2bf(a) | ((unsigned int)f2bf(b) << 16);
}
__device__ inline void unpack8(uint4 v, float* f) {
  union { unsigned int i; float g; } c;
  c.i = v.x << 16;          f[0] = c.g;
  c.i = v.x & 0xffff0000u;  f[1] = c.g;
  c.i = v.y << 16;          f[2] = c.g;
  c.i = v.y & 0xffff0000u;  f[3] = c.g;
  c.i = v.z << 16;          f[4] = c.g;
  c.i = v.z & 0xffff0000u;  f[5] = c.g;
  c.i = v.w << 16;          f[6] = c.g;
  c.i = v.w & 0xffff0000u;  f[7] = c.g;
}

// ---------------- workspace layout (bytes), ~38 MB ----------------
static const size_t OFF_QB = 0;           // q (pre-scaled 1/8) [48][1024][64] bf16
static const size_t OFF_KB = 6291456;     // k row-major [48][1024][64] bf16
static const size_t OFF_VT = 12582912;    // v transposed [48][64][1024] bf16
static const size_t OFF_UG = 18874368;    // U = M~ @ v, f32 [48][1024][64]
static const size_t OFF_OT = 31457280;    // o_tmp [8192,384] bf16
static const size_t OFF_ST = 37748736;    // stats 48*2 f32
static const size_t OFF_CS = 37749248;    // colsum_v 48*64 f32
static const size_t OFF_AD = 37761536;    // addend 48*64 f32
static const size_t OFF_AL = 37773824;    // alpha 48 f32

// ---------------- K1: qkv = x @ w_qkv^T (f32 in, bf16 staged); q*=1/8; scatter q,k,vT ----------------
__global__ __launch_bounds__(256) void k_qkv(const float* __restrict__ x,
                                             const float* __restrict__ w,
                                             u16* __restrict__ qb,
                                             u16* __restrict__ kb,
                                             u16* __restrict__ vT) {
  __shared__ u16 As[128 * 64];
  __shared__ u16 Bs[128 * 64];
  const int t = threadIdx.x;
  const int m0 = blockIdx.x * 128;
  const int n0 = blockIdx.y * 128;
  const int wave = t >> 6, lane = t & 63;
  const int wm = (wave & 1) * 64, wn = (wave >> 1) * 64;
  const int fr = lane & 15;
  const int fk = (lane >> 4) * 8;
  f32x4 acc[4][4] = {};
  for (int k0 = 0; k0 < 384; k0 += 64) {
#pragma unroll
    for (int i = 0; i < 4; ++i) {
      int e = (i * 256 + t) * 8;
      int row = e >> 6, col = e & 63;
      const float* xp = &x[(size_t)(m0 + row) * 384 + k0 + col];
      const float* wp = &w[(size_t)(n0 + row) * 384 + k0 + col];
      float4 a0 = *(const float4*)xp, a1 = *(const float4*)(xp + 4);
      uint4 av; av.x = pk2(a0.x, a0.y); av.y = pk2(a0.z, a0.w);
      av.z = pk2(a1.x, a1.y); av.w = pk2(a1.z, a1.w);
      *(uint4*)&As[e] = av;
      float4 b0 = *(const float4*)wp, b1 = *(const float4*)(wp + 4);
      uint4 bv; bv.x = pk2(b0.x, b0.y); bv.y = pk2(b0.z, b0.w);
      bv.z = pk2(b1.x, b1.y); bv.w = pk2(b1.z, b1.w);
      *(uint4*)&Bs[e] = bv;
    }
    __syncthreads();
#pragma unroll
    for (int ks = 0; ks < 2; ++ks) {
      const int ko = ks * 32 + fk;
      short8 a[4], b[4];
#pragma unroll
      for (int mi = 0; mi < 4; ++mi) a[mi] = *(const short8*)&As[(wm + mi * 16 + fr) * 64 + ko];
#pragma unroll
      for (int ni = 0; ni < 4; ++ni) b[ni] = *(const short8*)&Bs[(wn + ni * 16 + fr) * 64 + ko];
#pragma unroll
      for (int mi = 0; mi < 4; ++mi)
#pragma unroll
        for (int ni = 0; ni < 4; ++ni) acc[mi][ni] = MFMA(a[mi], b[ni], acc[mi][ni]);
    }
    __syncthreads();
  }
#pragma unroll
  for (int mi = 0; mi < 4; ++mi) {
#pragma unroll
    for (int ni = 0; ni < 4; ++ni) {
      int gc = n0 + wn + ni * 16 + fr;            // 0..1151
      int s = gc / 384;
      int rem = gc - s * 384;
      int h = rem >> 6, d = rem & 63;
#pragma unroll
      for (int r = 0; r < 4; ++r) {
        int gm = m0 + wm + mi * 16 + (lane >> 4) * 4 + r;   // 0..8191
        int b_ = gm >> 10, n = gm & 1023;
        size_t base = (size_t)(b_ * 6 + h) << 16;
        if (s == 0)      qb[base + (size_t)n * 64 + d] = f2bf(acc[mi][ni][r] * 0.125f);
        else if (s == 1) kb[base + (size_t)n * 64 + d] = f2bf(acc[mi][ni][r]);
        else             vT[base + (size_t)d * 1024 + n] = f2bf(acc[mi][ni][r]);
      }
    }
  }
}

// ---------------- colsum_v[bh][d] = sum_n v[n][d] ----------------
__global__ __launch_bounds__(256) void k_colsum(const u16* __restrict__ vT,
                                                float* __restrict__ colsum) {
  __shared__ float acc[64];
  const int t = threadIdx.x;
  const int bh = blockIdx.x;
  if (t < 64) acc[t] = 0.f;
  __syncthreads();
  const int lane = t & 63;
  for (int c = 0; c < 32; ++c) {
    size_t l = (size_t)c * 2048 + (size_t)t * 8;
    uint4 u = *(const uint4*)&vT[((size_t)bh << 16) + l];
    float f[8];
    unpack8(u, f);
    float part = f[0] + f[1] + f[2] + f[3] + f[4] + f[5] + f[6] + f[7];
    for (int off = 32; off; off >>= 1) part += __shfl_xor(part, off, 64);
    if (lane == 0) atomicAdd(&acc[(int)(l >> 10)], part);
  }
  __syncthreads();
  if (t < 64) colsum[bh * 64 + t] = acc[t];
}

// ---------------- fused: S(on the fly) -> conv3x3 -> softmax -> Q=NP-1 (LDS)
//                  -> head-mix M~ -> stats + U = M~ @ v  ----------------
// (verified: bit-identical output to the unfused green pipeline, rounds 2/3 evidence)
__global__ __launch_bounds__(256) void k_fused(const u16* __restrict__ qb,
                                               const u16* __restrict__ kb,
                                               const u16* __restrict__ vT,
                                               const float* __restrict__ wkq,
                                               const float* __restrict__ wh,
                                               float* __restrict__ Ug,
                                               float* __restrict__ stats) {
  __shared__ u16 Sld[10 * 1048];      // S rows (conv layout, data at col+8); later M~ rows 0..7
  __shared__ u16 Qld[6 * 8 * 1024];   // Q = N*P-1 per head
  __shared__ u16 qld[16 * 72];        // q rows r0-1..r0+8 (16-pad), pre-scaled
  __shared__ u16 kld[128 * 72];       // k chunk [128 m][64 d]
  __shared__ float red[4];

  const int t = threadIdx.x;
  const int r0 = blockIdx.x * 8;
  const int b_ = blockIdx.y;
  const int wave = t >> 6, lane = t & 63;
  const int fr = lane & 15;
  const int quad = lane >> 4;
  const int half = t >> 7;
  const int m0c = (t & 127) * 8;

  if (t < 10) { Sld[t * 1048 + 7] = 0; Sld[t * 1048 + 1032] = 0; }  // conv halo pads

  for (int h = 0; h < 6; ++h) {
    const u16* qp = qb + ((size_t)(b_ * 6 + h) << 16);
    const u16* kp = kb + ((size_t)(b_ * 6 + h) << 16);
    // stage q rows (16 x 64; rows 0..9 = global rows r0-1..r0+8, OOB/pad rows = 0)
    if (t < 128) {
      int row = t >> 3, c8 = (t & 7) * 8;
      int g = r0 - 1 + row;
      uint4 v = make_uint4(0u, 0u, 0u, 0u);
      if (row < 10 && g >= 0 && g < 1024) v = *(const uint4*)&qp[(size_t)g * 64 + c8];
      *(uint4*)&qld[row * 72 + c8] = v;
    }
    // S rows via MFMA, m in chunks of 128
    for (int c = 0; c < 8; ++c) {
      __syncthreads();   // qld ready / prev chunk's MFMA done before kld overwrite
#pragma unroll
      for (int j = 0; j < 4; ++j) {
        int e = j * 2048 + t * 8;
        int row = e >> 6, col = e & 63;
        *(uint4*)&kld[row * 72 + col] = *(const uint4*)&kp[(size_t)(c * 128 + row) * 64 + col];
      }
      __syncthreads();
#pragma unroll
      for (int nt = 0; nt < 2; ++nt) {
        int ntile = wave * 2 + nt;
        f32x4 acc = {0.f, 0.f, 0.f, 0.f};
#pragma unroll
        for (int ks = 0; ks < 2; ++ks) {
          short8 a = *(const short8*)&qld[fr * 72 + ks * 32 + quad * 8];
          short8 b = *(const short8*)&kld[(ntile * 16 + fr) * 72 + ks * 32 + quad * 8];
          acc = MFMA(a, b, acc);
        }
        int m = c * 128 + ntile * 16 + fr;
#pragma unroll
        for (int r = 0; r < 4; ++r) {
          int ri = quad * 4 + r;
          if (ri < 10) Sld[ri * 1048 + 8 + m] = f2bf(acc[r]);
        }
      }
    }
    __syncthreads();   // S complete
    // conv 3x3 + softmax, write Q = 1024*P - 1 to Qld[h]
    float wv[9];
#pragma unroll
    for (int i = 0; i < 9; ++i) wv[i] = wkq[h * 9 + i];
    for (int pass = 0; pass < 4; ++pass) {
      int rr = pass * 2 + half;   // local output row 0..7
      float o8[8] = {0.f, 0.f, 0.f, 0.f, 0.f, 0.f, 0.f, 0.f};
#pragma unroll
      for (int i = 0; i < 3; ++i) {
        const u16* rowp = &Sld[(rr + i) * 1048 + 8];
        float left = bf2f(rowp[m0c - 1]);
        float md[8];
        unpack8(*(const uint4*)&rowp[m0c], md);
        float right = bf2f(rowp[m0c + 8]);
        float w0 = wv[i * 3 + 0], w1 = wv[i * 3 + 1], w2 = wv[i * 3 + 2];
        o8[0] += w0 * left + w1 * md[0] + w2 * md[1];
#pragma unroll
        for (int j = 1; j < 7; ++j) o8[j] += w0 * md[j - 1] + w1 * md[j] + w2 * md[j + 1];
        o8[7] += w0 * md[6] + w1 * md[7] + w2 * right;
      }
      float mx = o8[0];
#pragma unroll
      for (int j = 1; j < 8; ++j) mx = fmaxf(mx, o8[j]);
      for (int off = 32; off; off >>= 1) mx = fmaxf(mx, __shfl_xor(mx, off, 64));
      if (lane == 0) red[t >> 6] = mx;
      __syncthreads();
      float rmax = fmaxf(red[half * 2], red[half * 2 + 1]);
      __syncthreads();
      float e8[8], s = 0.f;
#pragma unroll
      for (int j = 0; j < 8; ++j) { e8[j] = __expf(o8[j] - rmax); s += e8[j]; }
      for (int off = 32; off; off >>= 1) s += __shfl_xor(s, off, 64);
      if (lane == 0) red[t >> 6] = s;
      __syncthreads();
      float rsum = red[half * 2] + red[half * 2 + 1];
      __syncthreads();
      float scale = 1024.f / rsum;
      unsigned int pk[4];
#pragma unroll
      for (int jj = 0; jj < 4; ++jj)
        pk[jj] = pk2(e8[2 * jj] * scale - 1.f, e8[2 * jj + 1] * scale - 1.f);
      *(uint4*)&Qld[h * 8192 + rr * 1024 + m0c] = make_uint4(pk[0], pk[1], pk[2], pk[3]);
    }
  }

  // mix + stats + PV per output head o
  for (int o = 0; o < 6; ++o) {
    __syncthreads();   // Qld complete / prev PV done before Sld(M~) overwrite
    float wo[6];
#pragma unroll
    for (int hh = 0; hh < 6; ++hh) wo[hh] = wh[o * 6 + hh];
    float s1 = 0.f, s2 = 0.f;
#pragma unroll
    for (int j = 0; j < 4; ++j) {
      int e = (j * 256 + t) * 8;
      int row = e >> 10, m = e & 1023;
      float acc8[8] = {0.f, 0.f, 0.f, 0.f, 0.f, 0.f, 0.f, 0.f};
#pragma unroll
      for (int hh = 0; hh < 6; ++hh) {
        float qf[8];
        unpack8(*(const uint4*)&Qld[hh * 8192 + row * 1024 + m], qf);
        float w = wo[hh];
#pragma unroll
        for (int k = 0; k < 8; ++k) acc8[k] += w * qf[k];
      }
      unsigned int pk[4];
#pragma unroll
      for (int k = 0; k < 4; ++k) pk[k] = pk2(acc8[2 * k], acc8[2 * k + 1]);
      *(uint4*)&Sld[row * 1048 + m] = make_uint4(pk[0], pk[1], pk[2], pk[3]);  // M~ rows
#pragma unroll
      for (int k = 0; k < 8; ++k) { s1 += acc8[k]; s2 += acc8[k] * acc8[k]; }
    }
    for (int off = 32; off; off >>= 1) {
      s1 += __shfl_xor(s1, off, 64);
      s2 += __shfl_xor(s2, off, 64);
    }
    if (lane == 0) {
      atomicAdd(&stats[(b_ * 6 + o) * 2 + 0], s1);
      atomicAdd(&stats[(b_ * 6 + o) * 2 + 1], s2);
    }
    __syncthreads();   // M~ ready
    // PV: wave w owns d-tile [w*16, w*16+16); K = m = 1024
    const u16* vp = vT + ((size_t)(b_ * 6 + o) << 16);
    f32x4 acc = {0.f, 0.f, 0.f, 0.f};
#pragma unroll 4
    for (int ks = 0; ks < 32; ++ks) {
      int k0 = ks * 32;
      short8 a;
      if (fr < 8) a = *(const short8*)&Sld[fr * 1048 + k0 + quad * 8];
      else a = short8{0, 0, 0, 0, 0, 0, 0, 0};
      short8 b = *(const short8*)&vp[(size_t)(wave * 16 + fr) * 1024 + k0 + quad * 8];
      acc = MFMA(a, b, acc);
    }
    int d = wave * 16 + fr;
#pragma unroll
    for (int r = 0; r < 4; ++r) {
      int row = quad * 4 + r;
      if (row < 8)
        Ug[((size_t)((b_ * 6 + o) * 1024 + r0 + row)) * 64 + d] = acc[r];
    }
  }
}

// ---------------- finalize GN constants ----------------
__global__ __launch_bounds__(256) void k_finalize(const float* __restrict__ stats,
                                                  const float* __restrict__ colsum,
                                                  const float* __restrict__ gn_w,
                                                  const float* __restrict__ gn_b,
                                                  float* __restrict__ addend,
                                                  float* __restrict__ alphaArr) {
  int gid = blockIdx.x * 256 + threadIdx.x;   // 0..3071
  int bo = gid >> 6, d = gid & 63;
  int o = bo % 6;
  float s1 = stats[bo * 2], s2 = stats[bo * 2 + 1];
  const float inv = 1.f / 1048576.f;
  float mu = s1 * inv;
  float var = s2 * inv - mu * mu;
  float alpha = gn_w[o] * rsqrtf(var + 1e-5f * 1048576.f);
  float beta = gn_b[o] - alpha * mu;
  addend[gid] = beta * colsum[gid];
  if (d == 0) alphaArr[bo] = alpha;
}

// ---------------- apply: o_tmp[b,n,o*64+d] = alpha*U + addend ----------------
__global__ __launch_bounds__(256) void k_apply(const float* __restrict__ Ug,
                                               const float* __restrict__ alphaArr,
                                               const float* __restrict__ addend,
                                               u16* __restrict__ otmp) {
  int i = blockIdx.x * 256 + threadIdx.x;
  int e = i * 4;
  int d4 = e & 63;
  int n = (e >> 6) & 1023;
  int bo = e >> 16;
  float al = alphaArr[bo];
  const float* ap = &addend[bo * 64 + d4];
  float4 u = *(const float4*)&Ug[e];
  int b = bo / 6, o = bo - b * 6;
  uint2 w;
  w.x = pk2(al * u.x + ap[0], al * u.y + ap[1]);
  w.y = pk2(al * u.z + ap[2], al * u.w + ap[3]);
  *(uint2*)&otmp[((size_t)(b * 1024 + n)) * 384 + o * 64 + d4] = w;
}

// ---------------- K6: out(F32) = o_tmp @ w_proj^T + b_proj ----------------
__global__ __launch_bounds__(256) void k_proj(const u16* __restrict__ A,
                                              const float* __restrict__ w,
                                              const float* __restrict__ bias,
                                              float* __restrict__ out) {
  __shared__ u16 As[128 * 64];
  __shared__ u16 Bs[128 * 64];
  const int t = threadIdx.x;
  const int m0 = blockIdx.x * 128;
  const int n0 = blockIdx.y * 128;
  const int wave = t >> 6, lane = t & 63;
  const int wm = (wave & 1) * 64, wn = (wave >> 1) * 64;
  const int fr = lane & 15;
  const int fk = (lane >> 4) * 8;
  f32x4 acc[4][4] = {};
  for (int k0 = 0; k0 < 384; k0 += 64) {
#pragma unroll
    for (int i = 0; i < 4; ++i) {
      int e = (i * 256 + t) * 8;
      int row = e >> 6, col = e & 63;
      *(uint4*)&As[e] = *(const uint4*)&A[(size_t)(m0 + row) * 384 + k0 + col];
      const float* wp = &w[(size_t)(n0 + row) * 384 + k0 + col];
      float4 b0 = *(const float4*)wp, b1 = *(const float4*)(wp + 4);
      uint4 bv; bv.x = pk2(b0.x, b0.y); bv.y = pk2(b0.z, b0.w);
      bv.z = pk2(b1.x, b1.y); bv.w = pk2(b1.z, b1.w);
      *(uint4*)&Bs[e] = bv;
    }
    __syncthreads();
#pragma unroll
    for (int ks = 0; ks < 2; ++ks) {
      const int ko = ks * 32 + fk;
      short8 a[4], b[4];
#pragma unroll
      for (int mi = 0; mi < 4; ++mi) a[mi] = *(const short8*)&As[(wm + mi * 16 + fr) * 64 + ko];
#pragma unroll
      for (int ni = 0; ni < 4; ++ni) b[ni] = *(const short8*)&Bs[(wn + ni * 16 + fr) * 64 + ko];
#pragma unroll
      for (int mi = 0; mi < 4; ++mi)
#pragma unroll
        for (int ni = 0; ni < 4; ++ni) acc[mi][ni] = MFMA(a[mi], b[ni], acc[mi][ni]);
    }
    __syncthreads();
  }
#pragma unroll
  for (int mi = 0; mi < 4; ++mi)
#pragma unroll
    for (int ni = 0; ni < 4; ++ni) {
      int gc = n0 + wn + ni * 16 + fr;
      float bv = bias[gc];
#pragma unroll
      for (int r = 0; r < 4; ++r) {
        int gm = m0 + wm + mi * 16 + (lane >> 4) * 4 + r;
        out[(size_t)gm * 384 + gc] = acc[mi][ni][r] + bv;   // FLOAT32 output
      }
    }
}

extern "C" void kernel_launch(void* const* d_in, const int* in_sizes, int n_in,
                              void* d_out, int out_size, void* d_ws, size_t ws_size,
                              hipStream_t stream) {
  (void)in_sizes; (void)n_in; (void)out_size; (void)ws_size;
  const float* x      = (const float*)d_in[0];
  const float* w_qkv  = (const float*)d_in[1];
  const float* w_proj = (const float*)d_in[2];
  const float* b_proj = (const float*)d_in[3];
  const float* w_kq   = (const float*)d_in[4];
  // d_in[5] b_kq: constant per map -> softmax-invariant, unused
  const float* w_head = (const float*)d_in[6];
  // d_in[7] b_head: constant per (b,o) map -> cancelled by GroupNorm, unused
  const float* gn_w   = (const float*)d_in[8];
  const float* gn_b   = (const float*)d_in[9];

  char* ws = (char*)d_ws;
  u16*   qb     = (u16*)(ws + OFF_QB);
  u16*   kb     = (u16*)(ws + OFF_KB);
  u16*   vT     = (u16*)(ws + OFF_VT);
  float* Ug     = (float*)(ws + OFF_UG);
  u16*   otmp   = (u16*)(ws + OFF_OT);
  float* stats  = (float*)(ws + OFF_ST);
  float* colsum = (float*)(ws + OFF_CS);
  float* addend = (float*)(ws + OFF_AD);
  float* alphaA = (float*)(ws + OFF_AL);

  hipMemsetAsync(stats, 0, 512, stream);
  k_qkv<<<dim3(64, 9), 256, 0, stream>>>(x, w_qkv, qb, kb, vT);
  k_colsum<<<dim3(48), 256, 0, stream>>>(vT, colsum);
  k_fused<<<dim3(128, 8), 256, 0, stream>>>(qb, kb, vT, w_kq, w_head, Ug, stats);
  k_finalize<<<dim3(12), 256, 0, stream>>>(stats, colsum, gn_w, gn_b, addend, alphaA);
  k_apply<<<dim3(3072), 256, 0, stream>>>(Ug, alphaA, addend, otmp);
  k_proj<<<dim3(64, 3), 256, 0, stream>>>(otmp, w_proj, b_proj, (float*)d_out);
}

// Round 8
// 329.158 us; speedup vs baseline: 2.5116x; 2.5116x over previous
//
#include <hip/hip_runtime.h>

typedef unsigned short u16;
typedef __attribute__((ext_vector_type(8))) short short8;
typedef __attribute__((ext_vector_type(4))) float f32x4;

#define MFMA(a, b, c) __builtin_amdgcn_mfma_f32_16x16x32_bf16((a), (b), (c), 0, 0, 0)

__device__ inline float bf2f(u16 u) {
  union { unsigned int i; float f; } w; w.i = ((unsigned int)u) << 16; return w.f;
}
__device__ inline u16 f2bf(float x) {
  union { float f; unsigned int i; } u; u.f = x;
  unsigned int r = u.i + 0x7fffu + ((u.i >> 16) & 1u);  // RNE
  return (u16)(r >> 16);
}
__device__ inline unsigned int pk2(float a, float b) {
  return (unsigned int)f2bf(a) | ((unsigned int)f2bf(b) << 16);
}
__device__ inline void unpack8(uint4 v, float* f) {
  union { unsigned int i; float g; } c;
  c.i = v.x << 16;          f[0] = c.g;
  c.i = v.x & 0xffff0000u;  f[1] = c.g;
  c.i = v.y << 16;          f[2] = c.g;
  c.i = v.y & 0xffff0000u;  f[3] = c.g;
  c.i = v.z << 16;          f[4] = c.g;
  c.i = v.z & 0xffff0000u;  f[5] = c.g;
  c.i = v.w << 16;          f[6] = c.g;
  c.i = v.w & 0xffff0000u;  f[7] = c.g;
}

// ---------------- workspace layout (bytes), ~226.5 MB (same footprint as green round 6) ----------------
static const size_t SZ_QKV = (size_t)48 * 1024 * 64 * 2;     // 6,291,456
static const size_t SZ_MAP = (size_t)48 * 1024 * 1024 * 2;   // 100,663,296
static const size_t OFF_Q  = 0;
static const size_t OFF_K  = OFF_Q + SZ_QKV;
static const size_t OFF_VT = OFF_K + SZ_QKV;
static const size_t OFF_S  = OFF_VT + SZ_QKV;                // S bf16 [48][1024][1024]
static const size_t OFF_QM = OFF_S + SZ_MAP;                 // Q = N*P-1 bf16 [48][1024][1024]
static const size_t OFF_OT = OFF_QM + SZ_MAP;                // o_tmp [B,N,C] bf16
static const size_t OFF_ST = OFF_OT + SZ_QKV;                // gram stats 8*27 f32 (896B slot)
static const size_t OFF_CS = OFF_ST + 896;                   // colsum_v 48*64 f32
static const size_t OFF_AD = OFF_CS + 12288;                 // addend 48*64 f32
static const size_t OFF_AL = OFF_AD + 12288;                 // alpha 48 f32

// ---------------- K1: qkv = x @ w_qkv^T (f32 in, bf16 staged), scatter to q,k,vT ----------------
__global__ __launch_bounds__(256) void k_qkv(const float* __restrict__ x,
                                             const float* __restrict__ w,
                                             u16* __restrict__ qb,
                                             u16* __restrict__ kb,
                                             u16* __restrict__ vT) {
  __shared__ u16 As[128 * 64];
  __shared__ u16 Bs[128 * 64];
  const int t = threadIdx.x;
  const int m0 = blockIdx.x * 128;
  const int n0 = blockIdx.y * 128;
  const int wave = t >> 6, lane = t & 63;
  const int wm = (wave & 1) * 64, wn = (wave >> 1) * 64;
  const int fr = lane & 15;
  const int fk = (lane >> 4) * 8;
  f32x4 acc[4][4] = {};
  for (int k0 = 0; k0 < 384; k0 += 64) {
#pragma unroll
    for (int i = 0; i < 4; ++i) {
      int e = (i * 256 + t) * 8;
      int row = e >> 6, col = e & 63;
      const float* xp = &x[(size_t)(m0 + row) * 384 + k0 + col];
      const float* wp = &w[(size_t)(n0 + row) * 384 + k0 + col];
      float4 a0 = *(const float4*)xp, a1 = *(const float4*)(xp + 4);
      uint4 av; av.x = pk2(a0.x, a0.y); av.y = pk2(a0.z, a0.w);
      av.z = pk2(a1.x, a1.y); av.w = pk2(a1.z, a1.w);
      *(uint4*)&As[e] = av;
      float4 b0 = *(const float4*)wp, b1 = *(const float4*)(wp + 4);
      uint4 bv; bv.x = pk2(b0.x, b0.y); bv.y = pk2(b0.z, b0.w);
      bv.z = pk2(b1.x, b1.y); bv.w = pk2(b1.z, b1.w);
      *(uint4*)&Bs[e] = bv;
    }
    __syncthreads();
#pragma unroll
    for (int ks = 0; ks < 2; ++ks) {
      const int ko = ks * 32 + fk;
      short8 a[4], b[4];
#pragma unroll
      for (int mi = 0; mi < 4; ++mi) a[mi] = *(const short8*)&As[(wm + mi * 16 + fr) * 64 + ko];
#pragma unroll
      for (int ni = 0; ni < 4; ++ni) b[ni] = *(const short8*)&Bs[(wn + ni * 16 + fr) * 64 + ko];
#pragma unroll
      for (int mi = 0; mi < 4; ++mi)
#pragma unroll
        for (int ni = 0; ni < 4; ++ni) acc[mi][ni] = MFMA(a[mi], b[ni], acc[mi][ni]);
    }
    __syncthreads();
  }
#pragma unroll
  for (int mi = 0; mi < 4; ++mi) {
#pragma unroll
    for (int ni = 0; ni < 4; ++ni) {
      int gc = n0 + wn + ni * 16 + fr;            // 0..1151
      int s = gc / 384;
      int rem = gc - s * 384;
      int h = rem >> 6, d = rem & 63;
#pragma unroll
      for (int r = 0; r < 4; ++r) {
        int gm = m0 + wm + mi * 16 + (lane >> 4) * 4 + r;   // 0..8191
        int b_ = gm >> 10, n = gm & 1023;
        u16 val = f2bf(acc[mi][ni][r]);
        size_t base = (size_t)(b_ * 6 + h) << 16;
        if (s == 0)      qb[base + (size_t)n * 64 + d] = val;
        else if (s == 1) kb[base + (size_t)n * 64 + d] = val;
        else             vT[base + (size_t)d * 1024 + n] = val;
      }
    }
  }
}

// ---------------- K2a: S = (q @ k^T) * SCALE, per (b,h) map ----------------
__global__ __launch_bounds__(256) void k_qk(const u16* __restrict__ qb,
                                            const u16* __restrict__ kb,
                                            u16* __restrict__ S) {
  __shared__ u16 As[128 * 64];
  __shared__ u16 Bs[128 * 64];
  const int t = threadIdx.x;
  const int m0 = blockIdx.x * 128, n0 = blockIdx.y * 128;
  const int bh = blockIdx.z;
  const u16* A = qb + ((size_t)bh << 16);
  const u16* Bp = kb + ((size_t)bh << 16);
  const int wave = t >> 6, lane = t & 63;
  const int wm = (wave & 1) * 64, wn = (wave >> 1) * 64;
  const int fr = lane & 15;
  const int fk = (lane >> 4) * 8;
  f32x4 acc[4][4] = {};
#pragma unroll
  for (int i = 0; i < 4; ++i) {
    int e = (i * 256 + t) * 8;
    *(uint4*)&As[e] = *(const uint4*)&A[(size_t)m0 * 64 + e];
    *(uint4*)&Bs[e] = *(const uint4*)&Bp[(size_t)n0 * 64 + e];
  }
  __syncthreads();
#pragma unroll
  for (int ks = 0; ks < 2; ++ks) {
    const int ko = ks * 32 + fk;
    short8 a[4], b[4];
#pragma unroll
    for (int mi = 0; mi < 4; ++mi) a[mi] = *(const short8*)&As[(wm + mi * 16 + fr) * 64 + ko];
#pragma unroll
    for (int ni = 0; ni < 4; ++ni) b[ni] = *(const short8*)&Bs[(wn + ni * 16 + fr) * 64 + ko];
#pragma unroll
    for (int mi = 0; mi < 4; ++mi)
#pragma unroll
      for (int ni = 0; ni < 4; ++ni) acc[mi][ni] = MFMA(a[mi], b[ni], acc[mi][ni]);
  }
  const size_t sb = (size_t)bh << 20;
#pragma unroll
  for (int mi = 0; mi < 4; ++mi)
#pragma unroll
    for (int ni = 0; ni < 4; ++ni) {
      int gc = n0 + wn + ni * 16 + fr;
#pragma unroll
      for (int r = 0; r < 4; ++r) {
        int gm = m0 + wm + mi * 16 + (lane >> 4) * 4 + r;
        S[sb + (size_t)gm * 1024 + gc] = f2bf(acc[mi][ni][r] * 0.125f);
      }
    }
}

// ---------------- K2b: depthwise 3x3 conv + softmax, Q = N*P - 1 (bf16) ----------------
__global__ __launch_bounds__(256) void k_conv_softmax(const u16* __restrict__ S,
                                                      const float* __restrict__ w_kq,
                                                      u16* __restrict__ Qb) {
  __shared__ u16 Sr[10 * 1040];
  __shared__ float red[4];
  const int t = threadIdx.x;
  const int bh = blockIdx.y;
  const int h = bh % 6;
  const int r0 = blockIdx.x * 8;
  const u16* Sp = S + ((size_t)bh << 20);
  float wv[9];
#pragma unroll
  for (int i = 0; i < 9; ++i) wv[i] = w_kq[h * 9 + i];
  if (t < 10) { Sr[t * 1040 + 7] = 0; Sr[t * 1040 + 1032] = 0; }
#pragma unroll
  for (int c = 0; c < 5; ++c) {
    int e = (c * 256 + t) * 8;
    int i = e >> 10, col = e & 1023;
    int g = r0 - 1 + i;
    uint4 val = make_uint4(0u, 0u, 0u, 0u);
    if (g >= 0 && g < 1024) val = *(const uint4*)&Sp[(size_t)g * 1024 + col];
    *(uint4*)&Sr[i * 1040 + 8 + col] = val;
  }
  __syncthreads();
  const int half = t >> 7;
  const int lane = t & 63;
  const int m0 = (t & 127) * 8;
  for (int pass = 0; pass < 4; ++pass) {
    int rr = pass * 2 + half;       // output row in block (0..7)
    float o8[8];
#pragma unroll
    for (int j = 0; j < 8; ++j) o8[j] = 0.f;
#pragma unroll
    for (int i = 0; i < 3; ++i) {
      const u16* rowp = &Sr[(rr + i) * 1040 + 8];
      float left = bf2f(rowp[m0 - 1]);
      float md[8];
      unpack8(*(const uint4*)&rowp[m0], md);
      float right = bf2f(rowp[m0 + 8]);
      float w0 = wv[i * 3 + 0], w1 = wv[i * 3 + 1], w2 = wv[i * 3 + 2];
      o8[0] += w0 * left + w1 * md[0] + w2 * md[1];
#pragma unroll
      for (int j = 1; j < 7; ++j) o8[j] += w0 * md[j - 1] + w1 * md[j] + w2 * md[j + 1];
      o8[7] += w0 * md[6] + w1 * md[7] + w2 * right;
    }
    float mx = o8[0];
#pragma unroll
    for (int j = 1; j < 8; ++j) mx = fmaxf(mx, o8[j]);
    for (int off = 32; off; off >>= 1) mx = fmaxf(mx, __shfl_xor(mx, off, 64));
    if (lane == 0) red[t >> 6] = mx;
    __syncthreads();
    float rmax = fmaxf(red[half * 2], red[half * 2 + 1]);
    __syncthreads();
    float e8[8], s = 0.f;
#pragma unroll
    for (int j = 0; j < 8; ++j) { e8[j] = __expf(o8[j] - rmax); s += e8[j]; }
    for (int off = 32; off; off >>= 1) s += __shfl_xor(s, off, 64);
    if (lane == 0) red[t >> 6] = s;
    __syncthreads();
    float rsum = red[half * 2] + red[half * 2 + 1];
    __syncthreads();
    float scale = 1024.f / rsum;
    unsigned int pk[4];
#pragma unroll
    for (int jj = 0; jj < 4; ++jj)
      pk[jj] = pk2(e8[2 * jj] * scale - 1.f, e8[2 * jj + 1] * scale - 1.f);
    int n = r0 + rr;
    *(uint4*)&Qb[((size_t)bh << 20) + (size_t)n * 1024 + m0] = make_uint4(pk[0], pk[1], pk[2], pk[3]);
  }
}

// ---------------- K3: Gram stats. gstats[b][0..5] = sum Q_h ; [6..26] = <Q_h,Q_h'> (h<=h') ----------------
// M~ is never materialized: var/mean of every head-mix follow from these 27 numbers.
__global__ __launch_bounds__(256) void k_gram(const u16* __restrict__ Qm,
                                              float* __restrict__ gstats) {
  __shared__ float red[4][27];
  const int t = threadIdx.x;
  const int n0 = blockIdx.x * 8;
  const int b_ = blockIdx.y;
  const size_t qbase = ((size_t)(b_ * 6)) << 20;
  uint4 buf[4][6];
#pragma unroll
  for (int p = 0; p < 4; ++p) {
    int e = (p * 256 + t) * 8;
    int row = e >> 10, m = e & 1023;
#pragma unroll
    for (int hh = 0; hh < 6; ++hh)
      buf[p][hh] = *(const uint4*)&Qm[qbase + (((size_t)hh) << 20) + (size_t)(n0 + row) * 1024 + m];
  }
  float s[6] = {0.f, 0.f, 0.f, 0.f, 0.f, 0.f};
  float G[21];
#pragma unroll
  for (int i = 0; i < 21; ++i) G[i] = 0.f;
#pragma unroll
  for (int p = 0; p < 4; ++p) {
    float qf[6][8];
#pragma unroll
    for (int hh = 0; hh < 6; ++hh) unpack8(buf[p][hh], qf[hh]);
#pragma unroll
    for (int j = 0; j < 8; ++j) {
      int idx = 0;
#pragma unroll
      for (int h1 = 0; h1 < 6; ++h1) {
        s[h1] += qf[h1][j];
#pragma unroll
        for (int h2 = h1; h2 < 6; ++h2) { G[idx] += qf[h1][j] * qf[h2][j]; ++idx; }
      }
    }
  }
  const int wave = t >> 6, lane = t & 63;
#pragma unroll
  for (int i = 0; i < 6; ++i) {
    float v = s[i];
    for (int off = 32; off; off >>= 1) v += __shfl_xor(v, off, 64);
    if (lane == 0) red[wave][i] = v;
  }
#pragma unroll
  for (int i = 0; i < 21; ++i) {
    float v = G[i];
    for (int off = 32; off; off >>= 1) v += __shfl_xor(v, off, 64);
    if (lane == 0) red[wave][6 + i] = v;
  }
  __syncthreads();
  if (t < 27)
    atomicAdd(&gstats[b_ * 27 + t], red[0][t] + red[1][t] + red[2][t] + red[3][t]);
}

// ---------------- K3b: colsum_v[bh][d] = sum_n vT[bh][d][n] ----------------
__global__ __launch_bounds__(256) void k_colsum(const u16* __restrict__ vT,
                                                float* __restrict__ colsum) {
  __shared__ float acc[64];
  const int t = threadIdx.x;
  const int bh = blockIdx.x;
  if (t < 64) acc[t] = 0.f;
  __syncthreads();
  const int lane = t & 63;
  for (int c = 0; c < 32; ++c) {
    size_t l = (size_t)c * 2048 + (size_t)t * 8;
    uint4 u = *(const uint4*)&vT[((size_t)bh << 16) + l];
    float f[8];
    unpack8(u, f);
    float part = f[0] + f[1] + f[2] + f[3] + f[4] + f[5] + f[6] + f[7];
    for (int off = 32; off; off >>= 1) part += __shfl_xor(part, off, 64);
    if (lane == 0) atomicAdd(&acc[(int)(l >> 10)], part);
  }
  __syncthreads();
  if (t < 64) colsum[bh * 64 + t] = acc[t];
}

// ---------------- K4: finalize GN constants from Gram ----------------
// s1 = w_o . s ; s2 = w_o^T G w_o ; mu = s1/N^2 ; var = s2/N^2 - mu^2
__global__ __launch_bounds__(256) void k_finalize(const float* __restrict__ gstats,
                                                  const float* __restrict__ colsum,
                                                  const float* __restrict__ wh,
                                                  const float* __restrict__ gn_w,
                                                  const float* __restrict__ gn_b,
                                                  float* __restrict__ addend,
                                                  float* __restrict__ alphaArr) {
  int gid = blockIdx.x * 256 + threadIdx.x;   // 0..3071
  int bo = gid >> 6, d = gid & 63;
  int b_ = bo / 6, o = bo - b_ * 6;
  const float* g = &gstats[b_ * 27];
  float w[6];
#pragma unroll
  for (int hh = 0; hh < 6; ++hh) w[hh] = wh[o * 6 + hh];
  float s1 = 0.f;
#pragma unroll
  for (int hh = 0; hh < 6; ++hh) s1 += w[hh] * g[hh];
  float s2 = 0.f;
  int idx = 6;
#pragma unroll
  for (int h1 = 0; h1 < 6; ++h1)
#pragma unroll
    for (int h2 = h1; h2 < 6; ++h2) {
      float c = g[idx]; ++idx;
      s2 += (h1 == h2 ? w[h1] * w[h1] : 2.f * w[h1] * w[h2]) * c;
    }
  const float inv = 1.f / 1048576.f;
  float mu = s1 * inv;
  float var = s2 * inv - mu * mu;
  float alpha = gn_w[o] * rsqrtf(var + 1e-5f * 1048576.f);
  float beta = gn_b[o] - alpha * mu;
  addend[gid] = beta * colsum[gid];
  if (d == 0) alphaArr[bo] = alpha;
}

// ---------------- K5: PV with mix-on-the-fly + fused GN apply ----------------
// Per (bo, 64-row tile): A~ = sum_h w[o,h]*Q_h staged per 64-m chunk, U += A~ @ v (MFMA),
// epilogue writes o_tmp = alpha*U + addend (bf16).
__global__ __launch_bounds__(256) void k_pvmix(const u16* __restrict__ Qm,
                                               const u16* __restrict__ vT,
                                               const float* __restrict__ wh,
                                               const float* __restrict__ alphaArr,
                                               const float* __restrict__ addend,
                                               u16* __restrict__ otmp) {
  __shared__ u16 Am[64 * 72];
  __shared__ u16 Vm[64 * 72];
  const int t = threadIdx.x;
  const int n0 = blockIdx.x * 64;
  const int bo = blockIdx.y;
  const int b_ = bo / 6, o = bo - b_ * 6;
  const int wave = t >> 6, lane = t & 63;
  const int fr = lane & 15, quad = lane >> 4;
  float wo[6];
#pragma unroll
  for (int hh = 0; hh < 6; ++hh) wo[hh] = wh[o * 6 + hh];
  const size_t qbase = ((size_t)(b_ * 6)) << 20;
  const u16* vp = vT + ((size_t)bo << 16);
  f32x4 acc[4] = {};
  for (int mc = 0; mc < 16; ++mc) {
    const int mbase = mc * 64;
    // stage A~ (mix 6 heads in registers)
#pragma unroll
    for (int i = 0; i < 2; ++i) {
      int it = i * 256 + t;            // 0..511
      int row = it >> 3, mg = it & 7;
      int m = mbase + mg * 8;
      float mix[8] = {0.f, 0.f, 0.f, 0.f, 0.f, 0.f, 0.f, 0.f};
#pragma unroll
      for (int hh = 0; hh < 6; ++hh) {
        float qf[8];
        unpack8(*(const uint4*)&Qm[qbase + (((size_t)hh) << 20) + (size_t)(n0 + row) * 1024 + m], qf);
        float w = wo[hh];
#pragma unroll
        for (int j = 0; j < 8; ++j) mix[j] += w * qf[j];
      }
      uint4 pk4;
      pk4.x = pk2(mix[0], mix[1]); pk4.y = pk2(mix[2], mix[3]);
      pk4.z = pk2(mix[4], mix[5]); pk4.w = pk2(mix[6], mix[7]);
      *(uint4*)&Am[row * 72 + mg * 8] = pk4;
    }
    // stage v tile [64 d][64 m] from vT
#pragma unroll
    for (int i = 0; i < 2; ++i) {
      int it = i * 256 + t;
      int d = it >> 3, mg = it & 7;
      *(uint4*)&Vm[d * 72 + mg * 8] = *(const uint4*)&vp[(size_t)d * 1024 + mbase + mg * 8];
    }
    __syncthreads();
#pragma unroll
    for (int ks = 0; ks < 2; ++ks) {
      short8 a = *(const short8*)&Am[(wave * 16 + fr) * 72 + ks * 32 + quad * 8];
#pragma unroll
      for (int ni = 0; ni < 4; ++ni) {
        short8 b = *(const short8*)&Vm[(ni * 16 + fr) * 72 + ks * 32 + quad * 8];
        acc[ni] = MFMA(a, b, acc[ni]);
      }
    }
    __syncthreads();
  }
  const float alpha = alphaArr[bo];
#pragma unroll
  for (int ni = 0; ni < 4; ++ni) {
    int d = ni * 16 + fr;
    float add = addend[bo * 64 + d];
#pragma unroll
    for (int r = 0; r < 4; ++r) {
      int n = n0 + wave * 16 + quad * 4 + r;
      otmp[((size_t)(b_ * 1024 + n)) * 384 + o * 64 + d] = f2bf(acc[ni][r] * alpha + add);
    }
  }
}

// ---------------- K6: out(F32) = o_tmp @ w_proj^T + b_proj ----------------
__global__ __launch_bounds__(256) void k_proj(const u16* __restrict__ A,
                                              const float* __restrict__ w,
                                              const float* __restrict__ bias,
                                              float* __restrict__ out) {
  __shared__ u16 As[128 * 64];
  __shared__ u16 Bs[128 * 64];
  const int t = threadIdx.x;
  const int m0 = blockIdx.x * 128;
  const int n0 = blockIdx.y * 128;
  const int wave = t >> 6, lane = t & 63;
  const int wm = (wave & 1) * 64, wn = (wave >> 1) * 64;
  const int fr = lane & 15;
  const int fk = (lane >> 4) * 8;
  f32x4 acc[4][4] = {};
  for (int k0 = 0; k0 < 384; k0 += 64) {
#pragma unroll
    for (int i = 0; i < 4; ++i) {
      int e = (i * 256 + t) * 8;
      int row = e >> 6, col = e & 63;
      *(uint4*)&As[e] = *(const uint4*)&A[(size_t)(m0 + row) * 384 + k0 + col];
      const float* wp = &w[(size_t)(n0 + row) * 384 + k0 + col];
      float4 b0 = *(const float4*)wp, b1 = *(const float4*)(wp + 4);
      uint4 bv; bv.x = pk2(b0.x, b0.y); bv.y = pk2(b0.z, b0.w);
      bv.z = pk2(b1.x, b1.y); bv.w = pk2(b1.z, b1.w);
      *(uint4*)&Bs[e] = bv;
    }
    __syncthreads();
#pragma unroll
    for (int ks = 0; ks < 2; ++ks) {
      const int ko = ks * 32 + fk;
      short8 a[4], b[4];
#pragma unroll
      for (int mi = 0; mi < 4; ++mi) a[mi] = *(const short8*)&As[(wm + mi * 16 + fr) * 64 + ko];
#pragma unroll
      for (int ni = 0; ni < 4; ++ni) b[ni] = *(const short8*)&Bs[(wn + ni * 16 + fr) * 64 + ko];
#pragma unroll
      for (int mi = 0; mi < 4; ++mi)
#pragma unroll
        for (int ni = 0; ni < 4; ++ni) acc[mi][ni] = MFMA(a[mi], b[ni], acc[mi][ni]);
    }
    __syncthreads();
  }
#pragma unroll
  for (int mi = 0; mi < 4; ++mi)
#pragma unroll
    for (int ni = 0; ni < 4; ++ni) {
      int gc = n0 + wn + ni * 16 + fr;
      float bv = bias[gc];
#pragma unroll
      for (int r = 0; r < 4; ++r) {
        int gm = m0 + wm + mi * 16 + (lane >> 4) * 4 + r;
        out[(size_t)gm * 384 + gc] = acc[mi][ni][r] + bv;   // FLOAT32 output
      }
    }
}

extern "C" void kernel_launch(void* const* d_in, const int* in_sizes, int n_in,
                              void* d_out, int out_size, void* d_ws, size_t ws_size,
                              hipStream_t stream) {
  (void)in_sizes; (void)n_in; (void)out_size; (void)ws_size;
  const float* x      = (const float*)d_in[0];
  const float* w_qkv  = (const float*)d_in[1];
  const float* w_proj = (const float*)d_in[2];
  const float* b_proj = (const float*)d_in[3];
  const float* w_kq   = (const float*)d_in[4];
  // d_in[5] b_kq: constant per map -> softmax-invariant, unused
  const float* w_head = (const float*)d_in[6];
  // d_in[7] b_head: constant per (b,o) map -> cancelled by GroupNorm, unused
  const float* gn_w   = (const float*)d_in[8];
  const float* gn_b   = (const float*)d_in[9];

  char* ws = (char*)d_ws;
  u16*   qb      = (u16*)(ws + OFF_Q);
  u16*   kb      = (u16*)(ws + OFF_K);
  u16*   vT      = (u16*)(ws + OFF_VT);
  u16*   Sb      = (u16*)(ws + OFF_S);
  u16*   Qm      = (u16*)(ws + OFF_QM);
  u16*   otmp    = (u16*)(ws + OFF_OT);
  float* gstats  = (float*)(ws + OFF_ST);
  float* colsum  = (float*)(ws + OFF_CS);
  float* addend  = (float*)(ws + OFF_AD);
  float* alphaA  = (float*)(ws + OFF_AL);

  hipMemsetAsync(gstats, 0, 896, stream);
  k_qkv<<<dim3(64, 9), 256, 0, stream>>>(x, w_qkv, qb, kb, vT);
  k_qk<<<dim3(8, 8, 48), 256, 0, stream>>>(qb, kb, Sb);
  k_conv_softmax<<<dim3(128, 48), 256, 0, stream>>>(Sb, w_kq, Qm);
  k_gram<<<dim3(128, 8), 256, 0, stream>>>(Qm, gstats);
  k_colsum<<<dim3(48), 256, 0, stream>>>(vT, colsum);
  k_finalize<<<dim3(12), 256, 0, stream>>>(gstats, colsum, w_head, gn_w, gn_b, addend, alphaA);
  k_pvmix<<<dim3(16, 48), 256, 0, stream>>>(Qm, vT, w_head, alphaA, addend, otmp);
  k_proj<<<dim3(64, 3), 256, 0, stream>>>(otmp, w_proj, b_proj, (float*)d_out);
}